// Round 12
// baseline (238.518 us; speedup 1.0000x reference)
//
#include <hip/hip_runtime.h>

// Problem constants: B=4, N_TOK=16384, DIM=256, NH=8, NP=4, HD=32, H=W=128.
// M = 65536 rows.  Weights tiny (s=0.02) => bf16 GEMM error << 2% threshold.
//
// Structure: x pre-converted to bf16 once (xbf, stored in the ws region later
// reused for attn -- xbf is dead before k_sample writes attn). GEMMs: B
// col-slice (64 cols, 32KB) in LDS once per block, single barrier, then waves
// independently stream 32-row slabs, A bf16 global->reg with 2-deep prefetch.

typedef __attribute__((ext_vector_type(8))) short bf16x8;
typedef __attribute__((ext_vector_type(4))) float f32x4;

__device__ __forceinline__ short f2bf(float f) {
  unsigned u = __float_as_uint(f);
  u = u + 0x7FFFu + ((u >> 16) & 1u);   // round-to-nearest-even
  return (short)(u >> 16);
}
__device__ __forceinline__ float bf2f(short s) {
  return __uint_as_float(((unsigned)(unsigned short)s) << 16);
}

__device__ __forceinline__ void gload16(const void* g, void* l) {
  __builtin_amdgcn_global_load_lds(
      (const __attribute__((address_space(1))) unsigned int*)g,
      (__attribute__((address_space(3))) unsigned int*)l, 16, 0, 0);
}

// ---------------------------------------------------------------- k_prep
// b < 8192: convert x (16.7M f32) -> xbf bf16 (8 elems/thread).
// b >= 8192: weights -> wcat[384][256], wproj[256][256] bf16.
__global__ __launch_bounds__(256) void k_prep(
    const float* __restrict__ x,
    const float* __restrict__ v_w, const float* __restrict__ aw_w,
    const float* __restrict__ off_w, const float* __restrict__ proj_w,
    short* __restrict__ xbf, short* __restrict__ wcat, short* __restrict__ wproj)
{
  int b = blockIdx.x;
  if (b < 8192) {
    size_t t = ((size_t)b << 8) + threadIdx.x;       // 2,097,152 threads
    const f32x4* src = (const f32x4*)(x + (t << 3));
    f32x4 f0 = src[0], f1 = src[1];
    bf16x8 v;
#pragma unroll
    for (int j = 0; j < 4; ++j) { v[j] = f2bf(f0[j]); v[4 + j] = f2bf(f1[j]); }
    *(bf16x8*)(xbf + (t << 3)) = v;
  } else {
    int idx = (b - 8192) * 256 + threadIdx.x;        // < 163840
    if (idx < 384 * 256) {
      int row = idx >> 8;
      float val = 0.f;
      if (row < 256)      val = v_w[idx];
      else if (row < 288) val = aw_w[idx - 256 * 256];
      else if (row < 352) val = off_w[idx - 288 * 256];
      wcat[idx] = f2bf(val);
    } else {
      int j = idx - 384 * 256;
      wproj[j] = f2bf(proj_w[j]);
    }
  }
}

// ---------------------------------------------------------------- k_proj
// grid(256, 6): x = row-block (256 rows, 8 waves x 32), y = cp (64-col slice).
// LDS B-slice [64][256] bf16 = 32KB, 16B-group XOR-swizzled. A: bf16 from
// xbf, 2-deep prefetch. Single barrier. 256%8==0 => all cp passes of a given
// row-block land on the same XCD (L2-local x re-reads).
__global__ __launch_bounds__(512) void k_proj(
    const short* __restrict__ xbf, const short* __restrict__ wcat,
    const float* __restrict__ v_b, const float* __restrict__ aw_b,
    const float* __restrict__ off_b,
    unsigned short* __restrict__ vbuf,   // [32][16384][32] bf16 (= d_out lo)
    float* __restrict__ wts,             // [32][16384][4]  (softmaxed)
    float* __restrict__ offraw)          // [32][16384][4][2]
{
  __shared__ short Bs[64 * 256];
  const int tid  = threadIdx.x;
  const int wave = tid >> 6, lane = tid & 63;
  const int cp   = blockIdx.y;          // 0..5
  const int by   = blockIdx.x;          // 0..255
  const int cpb  = cp << 6;

  // ---- B stage: 2048 groups, 4 gload16/thread; linear dest, pre-swz source
#pragma unroll
  for (int i = 0; i < 4; ++i) {
    int f   = i * 512 + tid;
    int col = f >> 5, s = f & 31;
    int g   = (s & 24) | ((s & 7) ^ (col & 7));
    const short* src = wcat + (size_t)(cpb + col) * 256 + (g << 3);
    gload16(src, &Bs[(i * 512 + (wave << 6)) << 3]);
  }
  __syncthreads();   // only barrier

  const int lr = lane & 15, kg = lane >> 4;
  const int sr0 = (by << 8) + (wave << 5);
  const short* arow0 = xbf + (size_t)(sr0 + lr) * 256 + (kg << 3);
  const short* arow1 = xbf + (size_t)(sr0 + 16 + lr) * 256 + (kg << 3);

  f32x4 acc[2][4] = {};
  bf16x8 a0 = *(const bf16x8*)arow0;
  bf16x8 a1 = *(const bf16x8*)arow1;

#pragma unroll
  for (int ks = 0; ks < 8; ++ks) {
    bf16x8 n0, n1;
    if (ks < 7) {
      n0 = *(const bf16x8*)(arow0 + ((ks + 1) << 5));
      n1 = *(const bf16x8*)(arow1 + ((ks + 1) << 5));
    }
#pragma unroll
    for (int cf = 0; cf < 4; ++cf) {
      int col = (cf << 4) + lr;
      int g = (ks << 2) + kg;
      int s = (g & 24) | ((g & 7) ^ (col & 7));
      bf16x8 b = *(const bf16x8*)&Bs[(col << 8) + (s << 3)];
      acc[0][cf] = __builtin_amdgcn_mfma_f32_16x16x32_bf16(a0, b, acc[0][cf], 0, 0, 0);
      acc[1][cf] = __builtin_amdgcn_mfma_f32_16x16x32_bf16(a1, b, acc[1][cf], 0, 0, 0);
    }
    if (ks < 7) { a0 = n0; a1 = n1; }
  }

  // epilogue: C/D layout col=lane&15, row=kg*4+j  [m89-verified]
#pragma unroll
  for (int cf = 0; cf < 4; ++cf) {
    const int cbase = cpb + (cf << 4);
    if (cbase >= 352) continue;         // padding cols
#pragma unroll
    for (int rf = 0; rf < 2; ++rf) {
#pragma unroll
      for (int j = 0; j < 4; ++j) {
        int r = sr0 + (rf << 4) + (kg << 2) + j;
        int b_ = r >> 14, nn = r & 16383;
        float v = acc[rf][cf][j];
        if (cbase < 256) {
          int c = cbase + lr;
          int h = c >> 5, d = c & 31;
          float val = v + v_b[c];
          vbuf[(((size_t)((b_ << 3) + h) << 14) + nn) * 32 + d] = (unsigned short)f2bf(val);
        } else if (cbase < 288) {
          int q = cbase - 256 + lr;     // p = q&3 = lr&3 ; softmax over 4 lanes
          float val = v + aw_b[q];
          float mx = fmaxf(val, __shfl_xor(val, 1));
          mx = fmaxf(mx, __shfl_xor(mx, 2));
          float e = __expf(val - mx);
          float ssum = e + __shfl_xor(e, 1);
          ssum += __shfl_xor(ssum, 2);
          float w = __fdividef(e, ssum);
          int h = q >> 2, p = q & 3;
          wts[(((size_t)((b_ << 3) + h) << 14) + nn) * 4 + p] = w;
        } else {
          int q = cbase - 288 + lr;     // rest = q&7
          int h = q >> 3, rest = q & 7;
          offraw[(((size_t)((b_ << 3) + h) << 14) + nn) * 8 + rest] = v + off_b[q];
        }
      }
    }
  }
}

// ---------------------------------------------------------------- k_sample
// 4 lanes per (g,n) item; 16B ushort8 bf16 gathers; weights precomputed.
// NOTE: writes attn into the SAME ws region that held xbf (xbf dead here).
__global__ __launch_bounds__(256) void k_sample(
    const unsigned short* __restrict__ vbuf, const float* __restrict__ wts,
    const float* __restrict__ offraw, unsigned short* __restrict__ attn)
{
  const int tid  = threadIdx.x;
  const int item = (blockIdx.x << 6) + (tid >> 2);   // g*16384 + n
  const int q    = tid & 3;                          // d = 8q..8q+7
  const int g = item >> 14, n = item & 16383;
  const float px = (float)(n & 127), py = (float)(n >> 7);

  f32x4 w4 = *(const f32x4*)(wts + (size_t)item * 4);
  const f32x4* opv = (const f32x4*)(offraw + (size_t)item * 8);
  f32x4 o0 = opv[0], o1 = opv[1];
  float wv[4]  = {w4[0], w4[1], w4[2], w4[3]};
  float oxs[4] = {o0[0], o0[2], o1[0], o1[2]};
  float oys[4] = {o0[1], o0[3], o1[1], o1[3]};

  const unsigned short* vg = vbuf + (((size_t)g) << 19) + (q << 3);
  float o[8] = {};
#pragma unroll
  for (int p = 0; p < 4; ++p) {
    float gx = px + oxs[p], gy = py + oys[p];
    float x0f = floorf(gx), y0f = floorf(gy);
    float wx1 = gx - x0f, wx0 = 1.f - wx1;
    float wy1 = gy - y0f, wy0 = 1.f - wy1;
    int x0 = (int)x0f, y0 = (int)y0f;
    bool xv0 = (unsigned)x0 < 128u, xv1 = (unsigned)(x0 + 1) < 128u;
    bool yv0 = (unsigned)y0 < 128u, yv1 = (unsigned)(y0 + 1) < 128u;
    const unsigned short* base = vg + (((y0 << 7) + x0) << 5);
    bf16x8 c00 = {}, c10 = {}, c01 = {}, c11 = {};
    if (xv0 & yv0) c00 = *(const bf16x8*)(base);
    if (xv1 & yv0) c10 = *(const bf16x8*)(base + 32);
    if (xv0 & yv1) c01 = *(const bf16x8*)(base + 4096);
    if (xv1 & yv1) c11 = *(const bf16x8*)(base + 4128);
    float w00 = wv[p] * (wy0 * wx0), w10 = wv[p] * (wy0 * wx1);
    float w01 = wv[p] * (wy1 * wx0), w11 = wv[p] * (wy1 * wx1);
#pragma unroll
    for (int j = 0; j < 8; ++j)
      o[j] += w00 * bf2f(c00[j]) + w10 * bf2f(c10[j])
            + w01 * bf2f(c01[j]) + w11 * bf2f(c11[j]);
  }
  int b_ = g >> 3, h = g & 7;
  bf16x8 pk;
#pragma unroll
  for (int j = 0; j < 8; ++j) pk[j] = f2bf(o[j]);
  *(bf16x8*)(attn + ((((size_t)b_ << 14) + n) << 8) + (h << 5) + (q << 3)) = pk;
}

// ---------------------------------------------------------------- k_out
// grid(256, 4): x = row-block (256 rows, 8 waves x 32), y = cp (64-col slice
// of wproj).  Same structure as k_proj; A = attn bf16, 2-deep prefetch.
__global__ __launch_bounds__(512) void k_out(
    const unsigned short* __restrict__ attn, const short* __restrict__ wproj,
    const float* __restrict__ proj_b, float* __restrict__ out)
{
  __shared__ short Bs[64 * 256];
  const int tid  = threadIdx.x;
  const int wave = tid >> 6, lane = tid & 63;
  const int cp   = blockIdx.y;          // 0..3
  const int by   = blockIdx.x;          // 0..255
  const int cpb  = cp << 6;

#pragma unroll
  for (int i = 0; i < 4; ++i) {
    int f   = i * 512 + tid;
    int col = f >> 5, s = f & 31;
    int g   = (s & 24) | ((s & 7) ^ (col & 7));
    const short* src = wproj + (size_t)(cpb + col) * 256 + (g << 3);
    gload16(src, &Bs[(i * 512 + (wave << 6)) << 3]);
  }
  __syncthreads();

  const int lr = lane & 15, kg = lane >> 4;
  const int sr0 = (by << 8) + (wave << 5);
  const short* arow0 = (const short*)attn + (size_t)(sr0 + lr) * 256 + (kg << 3);
  const short* arow1 = (const short*)attn + (size_t)(sr0 + 16 + lr) * 256 + (kg << 3);

  f32x4 acc[2][4] = {};
  bf16x8 a0 = *(const bf16x8*)arow0;
  bf16x8 a1 = *(const bf16x8*)arow1;

#pragma unroll
  for (int ks = 0; ks < 8; ++ks) {
    bf16x8 n0, n1;
    if (ks < 7) {
      n0 = *(const bf16x8*)(arow0 + ((ks + 1) << 5));
      n1 = *(const bf16x8*)(arow1 + ((ks + 1) << 5));
    }
#pragma unroll
    for (int cf = 0; cf < 4; ++cf) {
      int col = (cf << 4) + lr;
      int g = (ks << 2) + kg;
      int s = (g & 24) | ((g & 7) ^ (col & 7));
      bf16x8 b = *(const bf16x8*)&Bs[(col << 8) + (s << 3)];
      acc[0][cf] = __builtin_amdgcn_mfma_f32_16x16x32_bf16(a0, b, acc[0][cf], 0, 0, 0);
      acc[1][cf] = __builtin_amdgcn_mfma_f32_16x16x32_bf16(a1, b, acc[1][cf], 0, 0, 0);
    }
    if (ks < 7) { a0 = n0; a1 = n1; }
  }

#pragma unroll
  for (int cf = 0; cf < 4; ++cf) {
    int c = cpb + (cf << 4) + lr;
    float pb = proj_b[c];
#pragma unroll
    for (int rf = 0; rf < 2; ++rf) {
#pragma unroll
      for (int j = 0; j < 4; ++j) {
        int r = sr0 + (rf << 4) + (kg << 2) + j;
        out[(size_t)r * 256 + c] = acc[rf][cf][j] + pb;
      }
    }
  }
}

// ---------------------------------------------------------------- launch
extern "C" void kernel_launch(void* const* d_in, const int* in_sizes, int n_in,
                              void* d_out, int out_size, void* d_ws, size_t ws_size,
                              hipStream_t stream)
{
  const float* x      = (const float*)d_in[0];
  const float* v_w    = (const float*)d_in[1];
  const float* v_b    = (const float*)d_in[2];
  const float* aw_w   = (const float*)d_in[3];
  const float* aw_b   = (const float*)d_in[4];
  const float* off_w  = (const float*)d_in[5];
  const float* off_b  = (const float*)d_in[6];
  const float* proj_w = (const float*)d_in[7];
  const float* proj_b = (const float*)d_in[8];
  float* out = (float*)d_out;

  char* ws = (char*)d_ws;
  short* wcat   = (short*)(ws + 0);               // 196,608 B
  short* wproj  = (short*)(ws + 262144);          // 131,072 B
  float* wts    = (float*)(ws + 1048576);         // 8,388,608 B (softmaxed)
  float* offraw = (float*)(ws + 9437184);         // 16,777,216 B
  // ws + 26,214,400 .. +32MB: first holds xbf (bf16 x), then is REUSED as
  // attn by k_sample (xbf dead after k_proj). Total ws footprint unchanged.
  short* xbf = (short*)(ws + 26214400);
  unsigned short* attn = (unsigned short*)(ws + 26214400);
  unsigned short* vbuf = (unsigned short*)d_out;  // d_out lo 32MB as bf16 v maps

  hipLaunchKernelGGL(k_prep,   dim3(8832),     dim3(256), 0, stream,
                     x, v_w, aw_w, off_w, proj_w, xbf, wcat, wproj);
  hipLaunchKernelGGL(k_proj,   dim3(256, 6),   dim3(512), 0, stream,
                     xbf, wcat, v_b, aw_b, off_b, vbuf, wts, offraw);
  hipLaunchKernelGGL(k_sample, dim3(8192),     dim3(256), 0, stream,
                     vbuf, wts, offraw, attn);
  hipLaunchKernelGGL(k_out,    dim3(256, 4),   dim3(512), 0, stream,
                     attn, wproj, proj_b, out);
}